// Round 8
// baseline (632.382 us; speedup 1.0000x reference)
//
#include <hip/hip_runtime.h>
#include <cstdint>

// ---------------------------------------------------------------------------
// dysOpt: Davis-Yin splitting, 262144 rows x 64 vars, dynamic T.
//
// x20 u-space iteration (U = 20*(z + C), CC = 20*C):
//   m'  = med3(U, CC, CC+20)            (= 20*(clamp(z,0,1) + C))
//   U+  = K1*m' - c[j]                  <- raw c (nothing rematerializable),
//                                          per-elem update independent of the
//                                          row reduction
//   Sx  = 0.05*(Sm' - 64*CC) ; t = K2*Sx - R
//   corr20 = t*(20/64) - 10 ; R+ = R - Sx + 32 ; CC+ = K1*CC + corr20
// Exact algebra vs reference; rescale rounding ~1 ulp/iter damped by the
// K1 = 0.9975 contraction (absmax has sat at the bf16 floor for 6 rounds).
//
// Layout: 8 elems/lane, 8 lanes/row, 8 rows/wave, 32768 waves.
// ROUND-8 RATIONALE: rounds 6/7 (16/32 elems/lane) paid a ~1.8x hidden VALU
// tax from AGPR/scratch spills (r7: VGPR=64 + FETCH 33->50MB + WRITE 66->86MB
// at unchanged duration). 8/lane state = U[8]+c[8]+temps ~ 28 VGPR -- the
// size class that has always matched static instruction counts (r2: VGPR=28,
// effective == static). Static: 31 VALU + 3 ds_swizzle per wave-iter.
//
// Structure: probe (8192 rows, checked every iter) -> Ts = max Tr <= T;
// pass1: P = Ts-2 unchecked iters, then checked to wave all-pass = ib
// (residual monotone per row => ib = max(P+1, wave-max Tr) <= T and the
// argmax wave reports exactly T); checkpoint z(ib), atomicMax T.
// pass2: resume ib -> T, +1 differentiable step, clamp, store.
// Check: 400*||dz||^2 = q2 - 2*dCC*q1 + 64*dCC^2 <= 400*TOL^2 = 0.04.
// ---------------------------------------------------------------------------

#ifndef JAX_PARTITIONABLE
#define JAX_PARTITIONABLE 1
#endif

#define BATCHN 262144
#define MAXIT  200
#define RPW    8                          // rows per wave (8 lanes/row)
#define NWAVES (BATCHN / RPW)             // 32768
#define PROBE_ROWS 8192
#define PROBE_WAVES (PROBE_ROWS / RPW)    // 1024

#define K1 0.9975f   // 1 - a^2
#define K2 1.9975f   // 2 - a^2

__device__ __forceinline__ void tf2x32(uint32_t x0, uint32_t x1,
                                       uint32_t& o0, uint32_t& o1) {
  const uint32_t k0 = 0u, k1 = 1u;                 // jax.random.key(1) -> [0,1]
  const uint32_t k2 = 0x1BD11BDAu ^ k0 ^ k1;
  x0 += k0; x1 += k1;
#define TFR(r) { x0 += x1; x1 = (x1 << (r)) | (x1 >> (32 - (r))); x1 ^= x0; }
  TFR(13) TFR(15) TFR(26) TFR(6)   x0 += k1; x1 += k2 + 1u;
  TFR(17) TFR(29) TFR(16) TFR(24)  x0 += k2; x1 += k0 + 2u;
  TFR(13) TFR(15) TFR(26) TFR(6)   x0 += k0; x1 += k1 + 3u;
  TFR(17) TFR(29) TFR(16) TFR(24)  x0 += k1; x1 += k2 + 4u;
  TFR(13) TFR(15) TFR(26) TFR(6)   x0 += k2; x1 += k0 + 5u;
#undef TFR
  o0 = x0; o1 = x1;
}

__device__ __forceinline__ float z0_at(uint32_t f) {
  uint32_t b;
#if JAX_PARTITIONABLE
  uint32_t o0, o1;
  tf2x32(0u, f, o0, o1);
  b = o0 ^ o1;
#else
  const uint32_t H = 8388608u;
  uint32_t lo = (f < H) ? f : (f - H);
  uint32_t o0, o1;
  tf2x32(lo, lo + H, o0, o1);
  b = (f < H) ? o0 : o1;
#endif
  return __uint_as_float((b >> 9) | 0x3f800000u) - 1.0f;
}

// 8-lane row reduction (lanes xor 1,2,4 hold one row)
__device__ __forceinline__ float reduce8(float v) {
  v += __shfl_xor(v, 1);
  v += __shfl_xor(v, 2);
  v += __shfl_xor(v, 4);
  return v;
}

// ---- fast iteration: 31 VALU + 3 DS per wave-iter, no convergence check ---
__device__ __forceinline__ void fast_iter(float U[8], const float c[8],
                                          float& CC, float& R) {
  const float Ch = CC + 20.0f;
  float m[8];
#pragma unroll
  for (int j = 0; j < 8; ++j) m[j] = __builtin_amdgcn_fmed3f(U[j], CC, Ch);
  float s = ((m[0] + m[1]) + (m[2] + m[3])) + ((m[4] + m[5]) + (m[6] + m[7]));
#pragma unroll
  for (int j = 0; j < 8; ++j) U[j] = __builtin_fmaf(K1, m[j], -c[j]);
  s = reduce8(s);                                     // Sm' over the row
  float Sx = 0.05f * __builtin_fmaf(-64.0f, CC, s);   // (Sm' - 64CC)/20
  float t  = __builtin_fmaf(K2, Sx, -R);
  float corr20 = __builtin_fmaf(t, 0.3125f, -10.0f);  // 20*(t/64 - 0.5)
  R = (R - Sx) + 32.0f;
  CC = __builtin_fmaf(K1, CC, corr20);
}

// ---- checked iteration: returns 400*||dz_row||^2 (replicated in the row) --
__device__ __forceinline__ float chk_iter(float U[8], const float c[8],
                                          float& CC, float& R) {
  const float Ch = CC + 20.0f;
  float m[8];
#pragma unroll
  for (int j = 0; j < 8; ++j) m[j] = __builtin_amdgcn_fmed3f(U[j], CC, Ch);
  float s = ((m[0] + m[1]) + (m[2] + m[3])) + ((m[4] + m[5]) + (m[6] + m[7]));
  float q1 = 0.0f, q2 = 0.0f;
#pragma unroll
  for (int j = 0; j < 8; ++j) {
    float un = __builtin_fmaf(K1, m[j], -c[j]);
    float d = un - U[j];
    q1 += d;
    q2 = __builtin_fmaf(d, d, q2);
    U[j] = un;
  }
  s = reduce8(s);
  float Sx = 0.05f * __builtin_fmaf(-64.0f, CC, s);
  float t  = __builtin_fmaf(K2, Sx, -R);
  float corr20 = __builtin_fmaf(t, 0.3125f, -10.0f);
  R = (R - Sx) + 32.0f;
  float CCn = __builtin_fmaf(K1, CC, corr20);
  float dCC = CCn - CC;
  CC = CCn;
  q1 = reduce8(q1);
  q2 = reduce8(q2);
  // 400*ds = q2 - 2*dCC*q1 + 64*dCC^2
  float a = __builtin_fmaf(64.0f, dCC, -2.0f * q1);
  return __builtin_fmaf(dCC, a, q2);
}

__device__ __forceinline__ void load_c(const float* __restrict__ cost,
                                       int base, float c[8]) {
  const float4 c0 = *(const float4*)(cost + base);
  const float4 c1 = *(const float4*)(cost + base + 4);
  c[0] = c0.x; c[1] = c0.y; c[2] = c0.z; c[3] = c0.w;
  c[4] = c1.x; c[5] = c1.y; c[6] = c1.z; c[7] = c1.w;
}

__device__ __forceinline__ void init_state(const float* __restrict__ cost,
                                           int base, float c[8], float U[8],
                                           float& CC, float& R) {
  load_c(cost, base, c);
  float r = 0.0f;
#pragma unroll
  for (int j = 0; j < 8; ++j) {
    float z0 = z0_at((uint32_t)(base + j));
    U[j] = 20.0f * z0;
    r = __builtin_fmaf(0.05f, c[j], r + z0);   // r += z0 + 0.05*c
  }
  R = reduce8(r);                               // R = Sz + a*Sc
  CC = 0.0f;
}

// --- probe: rows [0, PROBE_ROWS), checked every iter, atomicMax Ts ---------
__global__ __launch_bounds__(256) void dys_probe(
    const float* __restrict__ cost, int* __restrict__ Tsample) {
  const int lane = threadIdx.x & 63;
  const int gw = blockIdx.x * 4 + (threadIdx.x >> 6);
  const int base = (gw * RPW + (lane >> 3)) * 64 + (lane & 7) * 8;

  float c[8], U[8], CC, R;
  init_state(cost, base, c, U, CC, R);

  int ib = MAXIT;
  for (int i = 1; i <= MAXIT; ++i) {
    float ds = chk_iter(U, c, CC, R);
    if (__all(ds <= 0.04f)) { ib = i; break; }   // wave-max Tr
  }
  if (lane == 0) atomicMax(Tsample, ib);
}

// --- pass1: P unchecked iters, checked to wave all-pass; checkpoint --------
__global__ __launch_bounds__(256) void dys_pass1(
    const float* __restrict__ cost, const int* __restrict__ Tsample,
    int* __restrict__ Tglob, int* __restrict__ TrArr,
    float* __restrict__ zst) {
  const int lane = threadIdx.x & 63;
  const int gw = blockIdx.x * 4 + (threadIdx.x >> 6);
  const int base = (gw * RPW + (lane >> 3)) * 64 + (lane & 7) * 8;

  float c[8], U[8], CC, R;
  init_state(cost, base, c, U, CC, R);

  const int Ts = *Tsample;                 // uniform
  const int P = (Ts > 2) ? (Ts - 2) : 0;   // P+1 <= Ts <= T

  for (int i = 0; i < P; ++i) fast_iter(U, c, CC, R);

  int ib = MAXIT;
  for (int i = P + 1; i <= MAXIT; ++i) {
    float ds = chk_iter(U, c, CC, R);
    if (__all(ds <= 0.04f)) { ib = i; break; }
  }
  // ib = max(P+1, wave-max Tr) <= T; the argmax wave reports exactly T.

  const float CC05 = 0.05f * CC;           // z = 0.05*U - 0.05*CC
  float4 za, zb;
  za.x = __builtin_fmaf(0.05f, U[0], -CC05);
  za.y = __builtin_fmaf(0.05f, U[1], -CC05);
  za.z = __builtin_fmaf(0.05f, U[2], -CC05);
  za.w = __builtin_fmaf(0.05f, U[3], -CC05);
  zb.x = __builtin_fmaf(0.05f, U[4], -CC05);
  zb.y = __builtin_fmaf(0.05f, U[5], -CC05);
  zb.z = __builtin_fmaf(0.05f, U[6], -CC05);
  zb.w = __builtin_fmaf(0.05f, U[7], -CC05);
  *(float4*)(zst + base)     = za;
  *(float4*)(zst + base + 4) = zb;
  if (lane == 0) {
    TrArr[gw] = ib;
    atomicMax(Tglob, ib);
  }
}

// --- pass2: resume ib -> T, +1 differentiable step, clamp, store -----------
__global__ __launch_bounds__(256) void dys_pass2(
    const float* __restrict__ cost, const int* __restrict__ Tglob,
    const int* __restrict__ TrArr, const float* __restrict__ zst,
    float* __restrict__ out) {
  const int lane = threadIdx.x & 63;
  const int gw = blockIdx.x * 4 + (threadIdx.x >> 6);
  const int base = (gw * RPW + (lane >> 3)) * 64 + (lane & 7) * 8;

  float c[8], U[8];
  load_c(cost, base, c);
  const float4 za = *(const float4*)(zst + base);
  const float4 zb = *(const float4*)(zst + base + 4);
  U[0] = 20.0f * za.x; U[1] = 20.0f * za.y;
  U[2] = 20.0f * za.z; U[3] = 20.0f * za.w;
  U[4] = 20.0f * zb.x; U[5] = 20.0f * zb.y;
  U[6] = 20.0f * zb.z; U[7] = 20.0f * zb.w;
  float r = ((za.x + za.y) + (za.z + za.w)) + ((zb.x + zb.y) + (zb.z + zb.w));
#pragma unroll
  for (int j = 0; j < 8; ++j) r = __builtin_fmaf(0.05f, c[j], r);
  float CC = 0.0f;
  float R = reduce8(r);                    // R = Sz + a*Sc (invariant)

  const int T = *Tglob;
  const int ib = TrArr[gw];                // wave-uniform

  // (T - ib) lockstep iters to z(T), +1 differentiable step
  for (int i = ib; i <= T; ++i) fast_iter(U, c, CC, R);

  const float CC05 = 0.05f * CC;
  float4 oa, ob;
  oa.x = __builtin_amdgcn_fmed3f(__builtin_fmaf(0.05f, U[0], -CC05), 0.0f, 1.0f);
  oa.y = __builtin_amdgcn_fmed3f(__builtin_fmaf(0.05f, U[1], -CC05), 0.0f, 1.0f);
  oa.z = __builtin_amdgcn_fmed3f(__builtin_fmaf(0.05f, U[2], -CC05), 0.0f, 1.0f);
  oa.w = __builtin_amdgcn_fmed3f(__builtin_fmaf(0.05f, U[3], -CC05), 0.0f, 1.0f);
  ob.x = __builtin_amdgcn_fmed3f(__builtin_fmaf(0.05f, U[4], -CC05), 0.0f, 1.0f);
  ob.y = __builtin_amdgcn_fmed3f(__builtin_fmaf(0.05f, U[5], -CC05), 0.0f, 1.0f);
  ob.z = __builtin_amdgcn_fmed3f(__builtin_fmaf(0.05f, U[6], -CC05), 0.0f, 1.0f);
  ob.w = __builtin_amdgcn_fmed3f(__builtin_fmaf(0.05f, U[7], -CC05), 0.0f, 1.0f);
  *(float4*)(out + base)     = oa;
  *(float4*)(out + base + 4) = ob;
}

extern "C" void kernel_launch(void* const* d_in, const int* in_sizes, int n_in,
                              void* d_out, int out_size, void* d_ws,
                              size_t ws_size, hipStream_t stream) {
  const float* cost = (const float*)d_in[0];
  float* out = (float*)d_out;

  // ws: [0..4) Tglob ; [4..8) Tsample ; [1024..) TrArr[32768] ; then z ckpt
  int* Tglob   = (int*)d_ws;
  int* Tsample = (int*)d_ws + 1;
  const size_t TR_OFF = 1024;
  const size_t Z_OFF  = TR_OFF + (size_t)NWAVES * sizeof(int);  // 16B-aligned
  int*   TrArr = (int*)((char*)d_ws + TR_OFF);
  float* zst   = (float*)((char*)d_ws + Z_OFF);

  hipMemsetAsync(d_ws, 0, 8, stream);   // Tglob = Tsample = 0

  dim3 block(256);
  dys_probe<<<dim3(PROBE_WAVES / 4), block, 0, stream>>>(cost, Tsample);
  dys_pass1<<<dim3(NWAVES / 4), block, 0, stream>>>(cost, Tsample, Tglob,
                                                    TrArr, zst);
  dys_pass2<<<dim3(NWAVES / 4), block, 0, stream>>>(cost, Tglob, TrArr, zst,
                                                    out);
}

// Round 9
// 600.819 us; speedup vs baseline: 1.0525x; 1.0525x over previous
//
#include <hip/hip_runtime.h>
#include <cstdint>

// ---------------------------------------------------------------------------
// dysOpt: Davis-Yin splitting, 262144 rows x 64 vars, dynamic T.
//
// x20 u-space iteration (U = 20*(z + C), CC = 20*C):
//   m'  = med3(U, CC, CC+20)            (= 20*(clamp(z,0,1) + C))
//   U+  = K1*m' - c[j]                  (raw c; update independent of the
//                                        row reduction)
//   Sx  = 0.05*(Sm' - 64*CC) ; t = K2*Sx - R
//   corr20 = t*(20/64) - 10 ; R+ = R - Sx + 32 ; CC+ = K1*CC + corr20
// Exact algebra vs reference; rescale rounding ~1 ulp/iter damped by the
// K1 = 0.9975 contraction (absmax at the bf16 floor for 7 rounds).
//
// ROUND-9: round 8 was LDS-pipe-bound -- 3 __shfl_xor/iter lowered to
// ds_bpermute (shared per-CU pipe, ~6 cyc thpt + ~100 cyc latency, all 32
// waves in phase) -> 470us vs 179us VALU model, VALUBusy 74%. Fix: the
// 8-lane row butterfly is DPP-expressible (full-rate VALU, no LDS):
//   xor1 = quad_perm[1,0,3,2] (0xB1); xor2 = quad_perm[2,3,0,1] (0x4E);
//   xor4 = row_half_mirror (0x141) -- valid because after xor1+xor2 each
//   quad is uniform, and half-mirror maps each lane to the opposite quad
//   within its 8-lane half-row. Loop is now pure VALU (~34 instr/wave-iter).
//
// Layout: 8 elems/lane, 8 lanes/row, 8 rows/wave, 32768 waves (VGPR~24-28,
// the size class with no spill/remat tax -- r6/r7 showed 16/32-elem states
// pay ~1.8x hidden VALU via AGPR/scratch spills).
//
// Structure: probe (8192 rows, checked every iter) -> Ts = max Tr <= T;
// pass1: P = Ts-2 unchecked iters, then checked to wave all-pass = ib
// (residual monotone per row => ib = max(P+1, wave-max Tr) <= T, argmax wave
// reports exactly T); checkpoint z(ib), atomicMax T.
// pass2: resume ib -> T, +1 differentiable step, clamp, store.
// Check: 400*||dz||^2 = q2 - 2*dCC*q1 + 64*dCC^2 <= 400*TOL^2 = 0.04.
// ---------------------------------------------------------------------------

#ifndef JAX_PARTITIONABLE
#define JAX_PARTITIONABLE 1
#endif

#define BATCHN 262144
#define MAXIT  200
#define RPW    8                          // rows per wave (8 lanes/row)
#define NWAVES (BATCHN / RPW)             // 32768
#define PROBE_ROWS 8192
#define PROBE_WAVES (PROBE_ROWS / RPW)    // 1024

#define K1 0.9975f   // 1 - a^2
#define K2 1.9975f   // 2 - a^2

__device__ __forceinline__ void tf2x32(uint32_t x0, uint32_t x1,
                                       uint32_t& o0, uint32_t& o1) {
  const uint32_t k0 = 0u, k1 = 1u;                 // jax.random.key(1) -> [0,1]
  const uint32_t k2 = 0x1BD11BDAu ^ k0 ^ k1;
  x0 += k0; x1 += k1;
#define TFR(r) { x0 += x1; x1 = (x1 << (r)) | (x1 >> (32 - (r))); x1 ^= x0; }
  TFR(13) TFR(15) TFR(26) TFR(6)   x0 += k1; x1 += k2 + 1u;
  TFR(17) TFR(29) TFR(16) TFR(24)  x0 += k2; x1 += k0 + 2u;
  TFR(13) TFR(15) TFR(26) TFR(6)   x0 += k0; x1 += k1 + 3u;
  TFR(17) TFR(29) TFR(16) TFR(24)  x0 += k1; x1 += k2 + 4u;
  TFR(13) TFR(15) TFR(26) TFR(6)   x0 += k2; x1 += k0 + 5u;
#undef TFR
  o0 = x0; o1 = x1;
}

__device__ __forceinline__ float z0_at(uint32_t f) {
  uint32_t b;
#if JAX_PARTITIONABLE
  uint32_t o0, o1;
  tf2x32(0u, f, o0, o1);
  b = o0 ^ o1;
#else
  const uint32_t H = 8388608u;
  uint32_t lo = (f < H) ? f : (f - H);
  uint32_t o0, o1;
  tf2x32(lo, lo + H, o0, o1);
  b = (f < H) ? o0 : o1;
#endif
  return __uint_as_float((b >> 9) | 0x3f800000u) - 1.0f;
}

// DPP cross-lane add: v += v(from DPP-selected lane). Pure VALU, no LDS.
template <int CTRL>
__device__ __forceinline__ float dpp_add(float v) {
  int s = __builtin_amdgcn_mov_dpp(__float_as_int(v), CTRL, 0xF, 0xF, true);
  return v + __int_as_float(s);
}

// 8-lane row reduction, all-VALU (lanes xor 1,2,4 hold one row)
__device__ __forceinline__ float reduce8(float v) {
  v = dpp_add<0xB1>(v);    // quad_perm [1,0,3,2]  : xor 1
  v = dpp_add<0x4E>(v);    // quad_perm [2,3,0,1]  : xor 2
  v = dpp_add<0x141>(v);   // row_half_mirror      : cross-quad (xor 4 equiv.)
  return v;
}

// ---- fast iteration: ~34 VALU, zero DS, no convergence check --------------
__device__ __forceinline__ void fast_iter(float U[8], const float c[8],
                                          float& CC, float& R) {
  const float Ch = CC + 20.0f;
  float m[8];
#pragma unroll
  for (int j = 0; j < 8; ++j) m[j] = __builtin_amdgcn_fmed3f(U[j], CC, Ch);
  float s = ((m[0] + m[1]) + (m[2] + m[3])) + ((m[4] + m[5]) + (m[6] + m[7]));
#pragma unroll
  for (int j = 0; j < 8; ++j) U[j] = __builtin_fmaf(K1, m[j], -c[j]);
  s = reduce8(s);                                     // Sm' over the row
  float Sx = 0.05f * __builtin_fmaf(-64.0f, CC, s);   // (Sm' - 64CC)/20
  float t  = __builtin_fmaf(K2, Sx, -R);
  float corr20 = __builtin_fmaf(t, 0.3125f, -10.0f);  // 20*(t/64 - 0.5)
  R = (R - Sx) + 32.0f;
  CC = __builtin_fmaf(K1, CC, corr20);
}

// ---- checked iteration: returns 400*||dz_row||^2 (replicated in the row) --
__device__ __forceinline__ float chk_iter(float U[8], const float c[8],
                                          float& CC, float& R) {
  const float Ch = CC + 20.0f;
  float m[8];
#pragma unroll
  for (int j = 0; j < 8; ++j) m[j] = __builtin_amdgcn_fmed3f(U[j], CC, Ch);
  float s = ((m[0] + m[1]) + (m[2] + m[3])) + ((m[4] + m[5]) + (m[6] + m[7]));
  float q1 = 0.0f, q2 = 0.0f;
#pragma unroll
  for (int j = 0; j < 8; ++j) {
    float un = __builtin_fmaf(K1, m[j], -c[j]);
    float d = un - U[j];
    q1 += d;
    q2 = __builtin_fmaf(d, d, q2);
    U[j] = un;
  }
  s = reduce8(s);
  float Sx = 0.05f * __builtin_fmaf(-64.0f, CC, s);
  float t  = __builtin_fmaf(K2, Sx, -R);
  float corr20 = __builtin_fmaf(t, 0.3125f, -10.0f);
  R = (R - Sx) + 32.0f;
  float CCn = __builtin_fmaf(K1, CC, corr20);
  float dCC = CCn - CC;
  CC = CCn;
  q1 = reduce8(q1);
  q2 = reduce8(q2);
  // 400*ds = q2 - 2*dCC*q1 + 64*dCC^2
  float a = __builtin_fmaf(64.0f, dCC, -2.0f * q1);
  return __builtin_fmaf(dCC, a, q2);
}

__device__ __forceinline__ void load_c(const float* __restrict__ cost,
                                       int base, float c[8]) {
  const float4 c0 = *(const float4*)(cost + base);
  const float4 c1 = *(const float4*)(cost + base + 4);
  c[0] = c0.x; c[1] = c0.y; c[2] = c0.z; c[3] = c0.w;
  c[4] = c1.x; c[5] = c1.y; c[6] = c1.z; c[7] = c1.w;
}

__device__ __forceinline__ void init_state(const float* __restrict__ cost,
                                           int base, float c[8], float U[8],
                                           float& CC, float& R) {
  load_c(cost, base, c);
  float r = 0.0f;
#pragma unroll
  for (int j = 0; j < 8; ++j) {
    float z0 = z0_at((uint32_t)(base + j));
    U[j] = 20.0f * z0;
    r = __builtin_fmaf(0.05f, c[j], r + z0);   // r += z0 + 0.05*c
  }
  R = reduce8(r);                               // R = Sz + a*Sc
  CC = 0.0f;
}

// --- probe: rows [0, PROBE_ROWS), checked every iter, atomicMax Ts ---------
__global__ __launch_bounds__(256) void dys_probe(
    const float* __restrict__ cost, int* __restrict__ Tsample) {
  const int lane = threadIdx.x & 63;
  const int gw = blockIdx.x * 4 + (threadIdx.x >> 6);
  const int base = (gw * RPW + (lane >> 3)) * 64 + (lane & 7) * 8;

  float c[8], U[8], CC, R;
  init_state(cost, base, c, U, CC, R);

  int ib = MAXIT;
  for (int i = 1; i <= MAXIT; ++i) {
    float ds = chk_iter(U, c, CC, R);
    if (__all(ds <= 0.04f)) { ib = i; break; }   // wave-max Tr
  }
  if (lane == 0) atomicMax(Tsample, ib);
}

// --- pass1: P unchecked iters, checked to wave all-pass; checkpoint --------
__global__ __launch_bounds__(256) void dys_pass1(
    const float* __restrict__ cost, const int* __restrict__ Tsample,
    int* __restrict__ Tglob, int* __restrict__ TrArr,
    float* __restrict__ zst) {
  const int lane = threadIdx.x & 63;
  const int gw = blockIdx.x * 4 + (threadIdx.x >> 6);
  const int base = (gw * RPW + (lane >> 3)) * 64 + (lane & 7) * 8;

  float c[8], U[8], CC, R;
  init_state(cost, base, c, U, CC, R);

  const int Ts = *Tsample;                 // uniform
  const int P = (Ts > 2) ? (Ts - 2) : 0;   // P+1 <= Ts <= T

  for (int i = 0; i < P; ++i) fast_iter(U, c, CC, R);

  int ib = MAXIT;
  for (int i = P + 1; i <= MAXIT; ++i) {
    float ds = chk_iter(U, c, CC, R);
    if (__all(ds <= 0.04f)) { ib = i; break; }
  }
  // ib = max(P+1, wave-max Tr) <= T; the argmax wave reports exactly T.

  const float CC05 = 0.05f * CC;           // z = 0.05*U - 0.05*CC
  float4 za, zb;
  za.x = __builtin_fmaf(0.05f, U[0], -CC05);
  za.y = __builtin_fmaf(0.05f, U[1], -CC05);
  za.z = __builtin_fmaf(0.05f, U[2], -CC05);
  za.w = __builtin_fmaf(0.05f, U[3], -CC05);
  zb.x = __builtin_fmaf(0.05f, U[4], -CC05);
  zb.y = __builtin_fmaf(0.05f, U[5], -CC05);
  zb.z = __builtin_fmaf(0.05f, U[6], -CC05);
  zb.w = __builtin_fmaf(0.05f, U[7], -CC05);
  *(float4*)(zst + base)     = za;
  *(float4*)(zst + base + 4) = zb;
  if (lane == 0) {
    TrArr[gw] = ib;
    atomicMax(Tglob, ib);
  }
}

// --- pass2: resume ib -> T, +1 differentiable step, clamp, store -----------
__global__ __launch_bounds__(256) void dys_pass2(
    const float* __restrict__ cost, const int* __restrict__ Tglob,
    const int* __restrict__ TrArr, const float* __restrict__ zst,
    float* __restrict__ out) {
  const int lane = threadIdx.x & 63;
  const int gw = blockIdx.x * 4 + (threadIdx.x >> 6);
  const int base = (gw * RPW + (lane >> 3)) * 64 + (lane & 7) * 8;

  float c[8], U[8];
  load_c(cost, base, c);
  const float4 za = *(const float4*)(zst + base);
  const float4 zb = *(const float4*)(zst + base + 4);
  U[0] = 20.0f * za.x; U[1] = 20.0f * za.y;
  U[2] = 20.0f * za.z; U[3] = 20.0f * za.w;
  U[4] = 20.0f * zb.x; U[5] = 20.0f * zb.y;
  U[6] = 20.0f * zb.z; U[7] = 20.0f * zb.w;
  float r = ((za.x + za.y) + (za.z + za.w)) + ((zb.x + zb.y) + (zb.z + zb.w));
#pragma unroll
  for (int j = 0; j < 8; ++j) r = __builtin_fmaf(0.05f, c[j], r);
  float CC = 0.0f;
  float R = reduce8(r);                    // R = Sz + a*Sc (invariant)

  const int T = *Tglob;
  const int ib = TrArr[gw];                // wave-uniform

  // (T - ib) lockstep iters to z(T), +1 differentiable step
  for (int i = ib; i <= T; ++i) fast_iter(U, c, CC, R);

  const float CC05 = 0.05f * CC;
  float4 oa, ob;
  oa.x = __builtin_amdgcn_fmed3f(__builtin_fmaf(0.05f, U[0], -CC05), 0.0f, 1.0f);
  oa.y = __builtin_amdgcn_fmed3f(__builtin_fmaf(0.05f, U[1], -CC05), 0.0f, 1.0f);
  oa.z = __builtin_amdgcn_fmed3f(__builtin_fmaf(0.05f, U[2], -CC05), 0.0f, 1.0f);
  oa.w = __builtin_amdgcn_fmed3f(__builtin_fmaf(0.05f, U[3], -CC05), 0.0f, 1.0f);
  ob.x = __builtin_amdgcn_fmed3f(__builtin_fmaf(0.05f, U[4], -CC05), 0.0f, 1.0f);
  ob.y = __builtin_amdgcn_fmed3f(__builtin_fmaf(0.05f, U[5], -CC05), 0.0f, 1.0f);
  ob.z = __builtin_amdgcn_fmed3f(__builtin_fmaf(0.05f, U[6], -CC05), 0.0f, 1.0f);
  ob.w = __builtin_amdgcn_fmed3f(__builtin_fmaf(0.05f, U[7], -CC05), 0.0f, 1.0f);
  *(float4*)(out + base)     = oa;
  *(float4*)(out + base + 4) = ob;
}

extern "C" void kernel_launch(void* const* d_in, const int* in_sizes, int n_in,
                              void* d_out, int out_size, void* d_ws,
                              size_t ws_size, hipStream_t stream) {
  const float* cost = (const float*)d_in[0];
  float* out = (float*)d_out;

  // ws: [0..4) Tglob ; [4..8) Tsample ; [1024..) TrArr[32768] ; then z ckpt
  int* Tglob   = (int*)d_ws;
  int* Tsample = (int*)d_ws + 1;
  const size_t TR_OFF = 1024;
  const size_t Z_OFF  = TR_OFF + (size_t)NWAVES * sizeof(int);  // 16B-aligned
  int*   TrArr = (int*)((char*)d_ws + TR_OFF);
  float* zst   = (float*)((char*)d_ws + Z_OFF);

  hipMemsetAsync(d_ws, 0, 8, stream);   // Tglob = Tsample = 0

  dim3 block(256);
  dys_probe<<<dim3(PROBE_WAVES / 4), block, 0, stream>>>(cost, Tsample);
  dys_pass1<<<dim3(NWAVES / 4), block, 0, stream>>>(cost, Tsample, Tglob,
                                                    TrArr, zst);
  dys_pass2<<<dim3(NWAVES / 4), block, 0, stream>>>(cost, Tglob, TrArr, zst,
                                                    out);
}

// Round 10
// 408.572 us; speedup vs baseline: 1.5478x; 1.4705x over previous
//
#include <hip/hip_runtime.h>
#include <cstdint>

// ---------------------------------------------------------------------------
// dysOpt: Davis-Yin splitting, 262144 rows x 64 vars, dynamic T.
//
// x20 u-space iteration (U = 20*(z + C), CC = 20*C):
//   m'  = med3(U, CC, CC+20)      (= 20*(clamp(z,0,1)+C)), computed IN PLACE
//   U+  = K1*m' - c[j]            (raw c; fma modifier gives -c free)
//   Sx  = 0.05*(Sm' - 64*CC) ; t = K2*Sx - R
//   corr20 = t*(20/64) - 10 ; R+ = R - Sx + 32 ; CC+ = K1*CC + corr20
// Exact algebra vs reference; rescale rounding ~1 ulp/iter damped by the
// K1 = 0.9975 contraction (absmax at the bf16 floor for 8 rounds).
//
// ROUND-10 (from the cross-round instruction audit):
//  * 16 elems/lane, 4 lanes/row, 16 rows/wave (r6 shape): wide rows amortize
//    the per-wave-iter fixed costs (scalar chain, reduction, loop) that made
//    the 8-elem layout SLOWER (r8/r9: 8.1 eff VALU/row-iter vs r6's 6.7).
//  * asm(""eg:"+v") pins c[] and U[] -- compiler cannot rematerialize via
//    reload (r6's hidden ~50 instr/iter tax, VGPR_Count=32 proof).
//  * reduce4 = 2x quad_perm DPP (0xB1, 0x4E): pure VALU, intra-quad, no LDS
//    pipe (r8 lesson: ds_bpermute shared pipe -> 470us, VALUBusy 74%).
//  * __launch_bounds__(256,4): 128-reg budget, demand ~48 -> no spill
//    (r7 lesson: oversize state -> AGPR spill round-trips at full VALU cost).
// Static: 16 med3 + 16 part-sum adds + 16 fma + 3 combine + 4 dpp + 5 scalar
// = 60 instr/wave-iter for 16 rows -> model 158us for pass1.
//
// Structure: probe (8192 rows, checked every iter) -> Ts = max Tr <= T;
// pass1: P = Ts-2 unchecked iters, then checked to wave all-pass = ib
// (residual monotone per row => ib = max(P+1, wave-max Tr) <= T, the argmax
// wave reports exactly T); checkpoint z(ib), atomicMax T.
// pass2: resume ib -> T, +1 differentiable step, clamp, store.
// Check: 400*||dz||^2 = q2 - 2*dCC*q1 + 64*dCC^2 <= 400*TOL^2 = 0.04.
// ---------------------------------------------------------------------------

#ifndef JAX_PARTITIONABLE
#define JAX_PARTITIONABLE 1
#endif

#define BATCHN 262144
#define MAXIT  200
#define RPW    16                         // rows per wave (4 lanes/row)
#define NWAVES (BATCHN / RPW)             // 16384
#define PROBE_ROWS 8192
#define PROBE_WAVES (PROBE_ROWS / RPW)    // 512

#define K1 0.9975f   // 1 - a^2
#define K2 1.9975f   // 2 - a^2

__device__ __forceinline__ void tf2x32(uint32_t x0, uint32_t x1,
                                       uint32_t& o0, uint32_t& o1) {
  const uint32_t k0 = 0u, k1 = 1u;                 // jax.random.key(1) -> [0,1]
  const uint32_t k2 = 0x1BD11BDAu ^ k0 ^ k1;
  x0 += k0; x1 += k1;
#define TFR(r) { x0 += x1; x1 = (x1 << (r)) | (x1 >> (32 - (r))); x1 ^= x0; }
  TFR(13) TFR(15) TFR(26) TFR(6)   x0 += k1; x1 += k2 + 1u;
  TFR(17) TFR(29) TFR(16) TFR(24)  x0 += k2; x1 += k0 + 2u;
  TFR(13) TFR(15) TFR(26) TFR(6)   x0 += k0; x1 += k1 + 3u;
  TFR(17) TFR(29) TFR(16) TFR(24)  x0 += k1; x1 += k2 + 4u;
  TFR(13) TFR(15) TFR(26) TFR(6)   x0 += k2; x1 += k0 + 5u;
#undef TFR
  o0 = x0; o1 = x1;
}

__device__ __forceinline__ float z0_at(uint32_t f) {
  uint32_t b;
#if JAX_PARTITIONABLE
  uint32_t o0, o1;
  tf2x32(0u, f, o0, o1);
  b = o0 ^ o1;
#else
  const uint32_t H = 8388608u;
  uint32_t lo = (f < H) ? f : (f - H);
  uint32_t o0, o1;
  tf2x32(lo, lo + H, o0, o1);
  b = (f < H) ? o0 : o1;
#endif
  return __uint_as_float((b >> 9) | 0x3f800000u) - 1.0f;
}

// DPP cross-lane add within a quad: v += v(lane DPP-selected). Pure VALU.
template <int CTRL>
__device__ __forceinline__ float dpp_add(float v) {
  int s = __builtin_amdgcn_mov_dpp(__float_as_int(v), CTRL, 0xF, 0xF, true);
  return v + __int_as_float(s);
}

// 4-lane row reduction (row = one quad), all-VALU
__device__ __forceinline__ float reduce4(float v) {
  v = dpp_add<0xB1>(v);    // quad_perm [1,0,3,2] : xor 1
  v = dpp_add<0x4E>(v);    // quad_perm [2,3,0,1] : xor 2
  return v;
}

// ---- fast iteration: ~60 VALU for 16 rows, zero DS, no check --------------
__device__ __forceinline__ void fast_iter(float U[16], const float c[16],
                                          float& CC, float& R) {
  const float Ch = CC + 20.0f;
  float sp[4] = {0.0f, 0.0f, 0.0f, 0.0f};
#pragma unroll
  for (int j = 0; j < 16; ++j) {
    float m = __builtin_amdgcn_fmed3f(U[j], CC, Ch);   // in place: U_old dead
    sp[j & 3] += m;
    U[j] = __builtin_fmaf(K1, m, -c[j]);
  }
  float s = (sp[0] + sp[1]) + (sp[2] + sp[3]);
  s = reduce4(s);                                     // Sm' over the row
  float Sx = 0.05f * __builtin_fmaf(-64.0f, CC, s);   // (Sm' - 64CC)/20
  float t  = __builtin_fmaf(K2, Sx, -R);
  float corr20 = __builtin_fmaf(t, 0.3125f, -10.0f);  // 20*(t/64 - 0.5)
  R = (R - Sx) + 32.0f;
  CC = __builtin_fmaf(K1, CC, corr20);
}

// ---- checked iteration: returns 400*||dz_row||^2 (replicated in the row) --
__device__ __forceinline__ float chk_iter(float U[16], const float c[16],
                                          float& CC, float& R) {
  const float Ch = CC + 20.0f;
  float sp[4] = {0.0f, 0.0f, 0.0f, 0.0f};
  float q1a = 0.0f, q1b = 0.0f, q2a = 0.0f, q2b = 0.0f;
#pragma unroll
  for (int j = 0; j < 16; ++j) {
    float m = __builtin_amdgcn_fmed3f(U[j], CC, Ch);
    sp[j & 3] += m;
    float un = __builtin_fmaf(K1, m, -c[j]);
    float d = un - U[j];
    if (j & 1) { q1b += d; q2b = __builtin_fmaf(d, d, q2b); }
    else       { q1a += d; q2a = __builtin_fmaf(d, d, q2a); }
    U[j] = un;
  }
  float s = (sp[0] + sp[1]) + (sp[2] + sp[3]);
  s = reduce4(s);
  float Sx = 0.05f * __builtin_fmaf(-64.0f, CC, s);
  float t  = __builtin_fmaf(K2, Sx, -R);
  float corr20 = __builtin_fmaf(t, 0.3125f, -10.0f);
  R = (R - Sx) + 32.0f;
  float CCn = __builtin_fmaf(K1, CC, corr20);
  float dCC = CCn - CC;
  CC = CCn;
  float q1 = reduce4(q1a + q1b);
  float q2 = reduce4(q2a + q2b);
  // 400*ds = q2 - 2*dCC*q1 + 64*dCC^2
  float a = __builtin_fmaf(64.0f, dCC, -2.0f * q1);
  return __builtin_fmaf(dCC, a, q2);
}

__device__ __forceinline__ void load_c(const float* __restrict__ cost,
                                       int base, float c[16]) {
#pragma unroll
  for (int k = 0; k < 4; ++k) {
    const float4 cq = *(const float4*)(cost + base + 4 * k);
    c[4 * k + 0] = cq.x; c[4 * k + 1] = cq.y;
    c[4 * k + 2] = cq.z; c[4 * k + 3] = cq.w;
  }
}

// Pin value to a VGPR: asm-defined => compiler cannot remat via reload.
__device__ __forceinline__ void pin16(float v[16]) {
#pragma unroll
  for (int j = 0; j < 16; ++j) asm("" : "+v"(v[j]));
}

__device__ __forceinline__ void init_state(const float* __restrict__ cost,
                                           int base, float c[16], float U[16],
                                           float& CC, float& R) {
  load_c(cost, base, c);
  float r = 0.0f;
#pragma unroll
  for (int j = 0; j < 16; ++j) {
    float z0 = z0_at((uint32_t)(base + j));
    U[j] = 20.0f * z0;
    r = __builtin_fmaf(0.05f, c[j], r + z0);   // r += z0 + 0.05*c
  }
  pin16(c);                                     // forbid remat/reload of c
  pin16(U);
  R = reduce4(r);                               // R = Sz + a*Sc
  CC = 0.0f;
}

// --- probe: rows [0, PROBE_ROWS), checked every iter, atomicMax Ts ---------
__global__ __launch_bounds__(256, 4) void dys_probe(
    const float* __restrict__ cost, int* __restrict__ Tsample) {
  const int lane = threadIdx.x & 63;
  const int gw = blockIdx.x * 4 + (threadIdx.x >> 6);
  const int base = (gw * RPW + (lane >> 2)) * 64 + (lane & 3) * 16;

  float c[16], U[16], CC, R;
  init_state(cost, base, c, U, CC, R);

  int ib = MAXIT;
  for (int i = 1; i <= MAXIT; ++i) {
    float ds = chk_iter(U, c, CC, R);
    if (__all(ds <= 0.04f)) { ib = i; break; }   // wave-max Tr
  }
  if (lane == 0) atomicMax(Tsample, ib);
}

// --- pass1: P unchecked iters, checked to wave all-pass; checkpoint --------
__global__ __launch_bounds__(256, 4) void dys_pass1(
    const float* __restrict__ cost, const int* __restrict__ Tsample,
    int* __restrict__ Tglob, int* __restrict__ TrArr,
    float* __restrict__ zst) {
  const int lane = threadIdx.x & 63;
  const int gw = blockIdx.x * 4 + (threadIdx.x >> 6);
  const int base = (gw * RPW + (lane >> 2)) * 64 + (lane & 3) * 16;

  float c[16], U[16], CC, R;
  init_state(cost, base, c, U, CC, R);

  const int Ts = *Tsample;                 // uniform
  const int P = (Ts > 2) ? (Ts - 2) : 0;   // P+1 <= Ts <= T

  for (int i = 0; i < P; ++i) fast_iter(U, c, CC, R);

  int ib = MAXIT;
  for (int i = P + 1; i <= MAXIT; ++i) {
    float ds = chk_iter(U, c, CC, R);
    if (__all(ds <= 0.04f)) { ib = i; break; }
  }
  // ib = max(P+1, wave-max Tr) <= T; the argmax wave reports exactly T.

  const float CC05 = 0.05f * CC;           // z = 0.05*U - 0.05*CC
#pragma unroll
  for (int k = 0; k < 4; ++k) {
    float4 zq;
    zq.x = __builtin_fmaf(0.05f, U[4 * k + 0], -CC05);
    zq.y = __builtin_fmaf(0.05f, U[4 * k + 1], -CC05);
    zq.z = __builtin_fmaf(0.05f, U[4 * k + 2], -CC05);
    zq.w = __builtin_fmaf(0.05f, U[4 * k + 3], -CC05);
    *(float4*)(zst + base + 4 * k) = zq;
  }
  if (lane == 0) {
    TrArr[gw] = ib;
    atomicMax(Tglob, ib);
  }
}

// --- pass2: resume ib -> T, +1 differentiable step, clamp, store -----------
__global__ __launch_bounds__(256, 4) void dys_pass2(
    const float* __restrict__ cost, const int* __restrict__ Tglob,
    const int* __restrict__ TrArr, const float* __restrict__ zst,
    float* __restrict__ out) {
  const int lane = threadIdx.x & 63;
  const int gw = blockIdx.x * 4 + (threadIdx.x >> 6);
  const int base = (gw * RPW + (lane >> 2)) * 64 + (lane & 3) * 16;

  float c[16], U[16];
  load_c(cost, base, c);
  float r = 0.0f;
#pragma unroll
  for (int k = 0; k < 4; ++k) {
    const float4 zq = *(const float4*)(zst + base + 4 * k);
    U[4 * k + 0] = 20.0f * zq.x; U[4 * k + 1] = 20.0f * zq.y;
    U[4 * k + 2] = 20.0f * zq.z; U[4 * k + 3] = 20.0f * zq.w;
    r += (zq.x + zq.y) + (zq.z + zq.w);
  }
#pragma unroll
  for (int j = 0; j < 16; ++j) r = __builtin_fmaf(0.05f, c[j], r);
  pin16(c);
  pin16(U);
  float CC = 0.0f;
  float R = reduce4(r);                    // R = Sz + a*Sc (invariant)

  const int T = *Tglob;
  const int ib = TrArr[gw];                // wave-uniform

  // (T - ib) lockstep iters to z(T), +1 differentiable step
  for (int i = ib; i <= T; ++i) fast_iter(U, c, CC, R);

  const float CC05 = 0.05f * CC;
#pragma unroll
  for (int k = 0; k < 4; ++k) {
    float4 o;
    o.x = __builtin_amdgcn_fmed3f(
        __builtin_fmaf(0.05f, U[4 * k + 0], -CC05), 0.0f, 1.0f);
    o.y = __builtin_amdgcn_fmed3f(
        __builtin_fmaf(0.05f, U[4 * k + 1], -CC05), 0.0f, 1.0f);
    o.z = __builtin_amdgcn_fmed3f(
        __builtin_fmaf(0.05f, U[4 * k + 2], -CC05), 0.0f, 1.0f);
    o.w = __builtin_amdgcn_fmed3f(
        __builtin_fmaf(0.05f, U[4 * k + 3], -CC05), 0.0f, 1.0f);
    *(float4*)(out + base + 4 * k) = o;
  }
}

extern "C" void kernel_launch(void* const* d_in, const int* in_sizes, int n_in,
                              void* d_out, int out_size, void* d_ws,
                              size_t ws_size, hipStream_t stream) {
  const float* cost = (const float*)d_in[0];
  float* out = (float*)d_out;

  // ws: [0..4) Tglob ; [4..8) Tsample ; [1024..) TrArr[16384] ; then z ckpt
  int* Tglob   = (int*)d_ws;
  int* Tsample = (int*)d_ws + 1;
  const size_t TR_OFF = 1024;
  const size_t Z_OFF  = TR_OFF + (size_t)NWAVES * sizeof(int);  // 16B-aligned
  int*   TrArr = (int*)((char*)d_ws + TR_OFF);
  float* zst   = (float*)((char*)d_ws + Z_OFF);

  hipMemsetAsync(d_ws, 0, 8, stream);   // Tglob = Tsample = 0

  dim3 block(256);
  dys_probe<<<dim3(PROBE_WAVES / 4), block, 0, stream>>>(cost, Tsample);
  dys_pass1<<<dim3(NWAVES / 4), block, 0, stream>>>(cost, Tsample, Tglob,
                                                    TrArr, zst);
  dys_pass2<<<dim3(NWAVES / 4), block, 0, stream>>>(cost, Tglob, TrArr, zst,
                                                    out);
}